// Round 4
// baseline (684.778 us; speedup 1.0000x reference)
//
#include <hip/hip_runtime.h>
#include <hip/hip_bf16.h>

// B=8, H=W=128, C=F=256, 3x3 modulated conv (StyleGAN2), bf16 MFMA implicit GEMM.
// R4: (1) k_conv: B-fragments loaded global->registers (depth-2 prefetch, breg[3]),
//     A double-buffered LDS via global_load_lds, ONE barrier per c-chunk (vs 10/18).
//     (2) k_modw split into k_demod (coalesced reduction) + k_wmod (LDS transpose)
//     — old modw was ~180us of lane-strided 1KB loads.
// Note: SQ_LDS_BANK_CONFLICT 1.887e7 = 4 cyc * 4.72e6 ds_read_b128 = inherent b128
//       cost, not layout conflicts. Reduced ds_read count instead (4/tap vs 8).

#define NB 8
#define NH 128
#define NW 128
#define NC 256
#define NF 256

typedef __attribute__((ext_vector_type(8))) short bf16x8;
typedef __attribute__((ext_vector_type(4))) float f32x4;

// A LDS: per buffer: 3 rows(dh) x 4 planes(c-quad) x 130 pos(w+halo) x 16B, pitch 2080B
#define PA 2080
#define A_ROW (4 * PA)        // 8320
#define A_BUF (3 * A_ROW)     // 24960
#define LDS_BYTES (2 * A_BUF) // 49920 -> 3 blocks/CU

static __device__ __forceinline__ ushort f2bf(float v) {
    union { ushort u; __hip_bfloat16 h; } o;
    o.h = __float2bfloat16(v);
    return o.u;
}

__device__ __forceinline__ void gload16(const ushort* g, const char* l) {
    __builtin_amdgcn_global_load_lds(
        (const __attribute__((address_space(1))) void*)g,
        (__attribute__((address_space(3))) void*)l,
        16, 0, 0);
}

// ---------------- x fp32 -> bf16 ----------------
__global__ void k_cvt(const float* __restrict__ x, ushort* __restrict__ xbf) {
    size_t i = ((size_t)blockIdx.x * 256 + threadIdx.x) * 8;
    float4 a = *(const float4*)(x + i);
    float4 b = *(const float4*)(x + i + 4);
    union { ushort s[8]; uint4 u; } o;
    o.s[0] = f2bf(a.x); o.s[1] = f2bf(a.y);
    o.s[2] = f2bf(a.z); o.s[3] = f2bf(a.w);
    o.s[4] = f2bf(b.x); o.s[5] = f2bf(b.y);
    o.s[6] = f2bf(b.z); o.s[7] = f2bf(b.w);
    *(uint4*)(xbf + i) = o.u;
}

// ---------------- demod factors: invd[b][f] ----------------
// grid 8 (b), block 256 (thread = f). kern loads lane-coalesced (256B/instr).
__global__ void k_demod(const float* __restrict__ kern, const float* __restrict__ style,
                        float* __restrict__ invd) {
    int b = blockIdx.x;
    int f = threadIdx.x;
    float acc = 0.f;
#pragma unroll
    for (int t = 0; t < 9; ++t) {
        const float* kp = kern + (size_t)t * 256 * 256 + f;
#pragma unroll 8
        for (int c = 0; c < 256; ++c) {
            float s = style[b * 256 + c] + 1.0f;
            float w = kp[(size_t)c * 256] * s;
            acc += w * w;
        }
    }
    invd[b * 256 + f] = 1.0f / sqrtf(acc + 1e-8f);
}

// ---------------- modulated weights, transposed: wm[b][t][f][c] bf16 ----------------
// block handles (b, t, 64-f chunk); coalesced kern loads, LDS transpose, 16B stores.
__global__ void k_wmod(const float* __restrict__ kern, const float* __restrict__ style,
                       const float* __restrict__ invd, ushort* __restrict__ wm) {
    int blk = blockIdx.x;
    int fc = blk & 3;
    int t  = (blk >> 2) % 9;
    int b  = blk / 36;
    int f0 = fc * 64;
    __shared__ ushort tile[64 * 264];   // pitch 264 ushorts = 528B (16B aligned)
    int fl = threadIdx.x & 63;
    int cq = threadIdx.x >> 6;
    float dv = invd[b * 256 + f0 + fl];
    const float* kp = kern + (size_t)t * 256 * 256 + f0 + fl;
#pragma unroll 4
    for (int cc = 0; cc < 64; ++cc) {
        int c = cq * 64 + cc;
        float s = style[b * 256 + c] + 1.0f;
        tile[fl * 264 + c] = f2bf(kp[(size_t)c * 256] * s * dv);
    }
    __syncthreads();
    int f  = threadIdx.x >> 2;
    int c8 = threadIdx.x & 3;
    ushort* dst = wm + (((size_t)(b * 9 + t) * 256) + f0 + f) * 256;
#pragma unroll
    for (int j = 0; j < 8; ++j) {
        int c = (c8 + j * 4) * 8;
        *(uint4*)(dst + c) = *(const uint4*)(tile + f * 264 + c);
    }
}

// ---------------- conv as implicit GEMM ----------------
__global__ void __launch_bounds__(256, 3)
k_conv(const ushort* __restrict__ xbf, const ushort* __restrict__ wm,
       float* __restrict__ out) {
    const int bidx = blockIdx.x;
    const int b    = bidx & 7;        // XCD-locality: image b pinned per XCD
    const int rest = bidx >> 3;
    const int fh   = rest & 1;
    const int h    = rest >> 1;

    __shared__ __align__(16) char smem[LDS_BYTES];

    const int tid = threadIdx.x;
    const int wave = tid >> 6, lane = tid & 63;
    const int wm_ = wave & 1, wn_ = wave >> 1;   // 2x2 wave grid, 64x64 each
    const int lrow = lane & 15;
    const int quad = lane >> 4;

    // zero both A buffers (halo pos 0/129 + out-of-image rows stay zero forever)
    {
        const uint4 z = {0, 0, 0, 0};
        for (int i = tid; i < LDS_BYTES / 16; i += 256) ((uint4*)smem)[i] = z;
    }

    // B fragment pointers: wm[b][tap][f][c] — lane's frag is contiguous 16B.
    const ushort* pB[4];
#pragma unroll
    for (int ni = 0; ni < 4; ++ni) {
        int f = fh * 128 + wn_ * 64 + ni * 16 + lrow;
        pB[ni] = wm + ((size_t)(b * 9) * 256 + f) * 256 + quad * 8;
    }
    bf16x8 breg[3][4];
    // prologue: tap0 -> breg[0], tap1 -> breg[1]
#pragma unroll
    for (int ni = 0; ni < 4; ++ni) breg[0][ni] = *(const bf16x8*)(pB[ni]);
#pragma unroll
    for (int ni = 0; ni < 4; ++ni) breg[1][ni] = *(const bf16x8*)(pB[ni] + 65536);

    f32x4 acc[4][4];
    const f32x4 zero4 = {0.f, 0.f, 0.f, 0.f};
#pragma unroll
    for (int mi = 0; mi < 4; ++mi)
#pragma unroll
        for (int ni = 0; ni < 4; ++ni) acc[mi][ni] = zero4;

    const ushort* xb_base = xbf + (size_t)b * 128 * 128 * 256;

    __syncthreads();   // LDS zeroing complete before any DMA lands

    // stage A chunk0 -> buf0 (24 wave-loads, 6 per wave)
#pragma unroll
    for (int i = 0; i < 6; ++i) {
        int L = wave * 6 + i;
        int dh = L >> 3, rem = L & 7;
        int p = rem >> 1, half = rem & 1;
        int hp = h + dh - 1;
        if (hp >= 0 && hp < 128) {
            const ushort* g = xb_base + ((size_t)hp * 128 + half * 64 + lane) * 256 + p * 8;
            const char* l = smem + dh * A_ROW + p * PA + 16 + half * 1024;
            gload16(g, l);
        }
    }

    for (int k = 0; k < 8; ++k) {
        __syncthreads();   // A[k] resident (vmcnt drain had full chunk to overlap);
                           // all waves done reading A[k-1]'s buffer
        // stage A chunk k+1 into the other buffer — in flight during ALL of chunk k
        if (k < 7) {
            char* dstbuf = smem + ((k + 1) & 1) * A_BUF;
            int c0 = (k + 1) * 32;
#pragma unroll
            for (int i = 0; i < 6; ++i) {
                int L = wave * 6 + i;
                int dh = L >> 3, rem = L & 7;
                int p = rem >> 1, half = rem & 1;
                int hp = h + dh - 1;
                if (hp >= 0 && hp < 128) {
                    const ushort* g = xb_base + ((size_t)hp * 128 + half * 64 + lane) * 256 + c0 + p * 8;
                    const char* l = dstbuf + dh * A_ROW + p * PA + 16 + half * 1024;
                    gload16(g, l);
                }
            }
        }
        const char* abase = smem + (k & 1) * A_BUF;
#pragma unroll
        for (int t = 0; t < 9; ++t) {
            const int dh = t / 3, dw = t % 3;
            // depth-2 B prefetch: tap t prefetches tap t+2 (wrapping into next chunk)
            if (t < 7) {
#pragma unroll
                for (int ni = 0; ni < 4; ++ni)
                    breg[(t + 2) % 3][ni] = *(const bf16x8*)(pB[ni] + (t + 2) * 65536);
            } else if (k < 7) {
#pragma unroll
                for (int ni = 0; ni < 4; ++ni)
                    breg[(t + 2) % 3][ni] = *(const bf16x8*)(pB[ni] + (t - 7) * 65536 + 32);
            }
            bf16x8 af[4];
#pragma unroll
            for (int mi = 0; mi < 4; ++mi) {
                int s = wm_ * 64 + mi * 16 + lrow + dw;
                af[mi] = *(const bf16x8*)(abase + dh * A_ROW + quad * PA + s * 16);
            }
#pragma unroll
            for (int mi = 0; mi < 4; ++mi)
#pragma unroll
                for (int ni = 0; ni < 4; ++ni)
                    acc[mi][ni] = __builtin_amdgcn_mfma_f32_16x16x32_bf16(
                        af[mi], breg[t % 3][ni], acc[mi][ni], 0, 0, 0);
        }
#pragma unroll
        for (int ni = 0; ni < 4; ++ni) pB[ni] += 32;   // next c-chunk
    }

    // epilogue: C/D layout col=lane&15, row=quad*4+reg
    float* obase = out + (((size_t)b * 128 + h) * 128) * 256 + fh * 128;
#pragma unroll
    for (int mi = 0; mi < 4; ++mi) {
        int wrow = wm_ * 64 + mi * 16 + quad * 4;
#pragma unroll
        for (int ni = 0; ni < 4; ++ni) {
            int f = wn_ * 64 + ni * 16 + lrow;
            f32x4 v = acc[mi][ni];
#pragma unroll
            for (int r = 0; r < 4; ++r) {
                obase[(size_t)(wrow + r) * 256 + f] = v[r];
            }
        }
    }
}

extern "C" void kernel_launch(void* const* d_in, const int* in_sizes, int n_in,
                              void* d_out, int out_size, void* d_ws, size_t ws_size,
                              hipStream_t stream) {
    const float* x     = (const float*)d_in[0];   // [8,128,128,256]
    const float* style = (const float*)d_in[1];   // [8,1,1,256]
    const float* kern  = (const float*)d_in[2];   // [3,3,256,256]
    float* out = (float*)d_out;                   // [8,128,128,256]

    ushort* xbf  = (ushort*)d_ws;                               // 64 MiB
    ushort* wmod = xbf + (size_t)NB * NH * NW * NC;             // 9 MiB
    float*  invd = (float*)(wmod + (size_t)NB * 9 * NF * NC);   // 8 KiB

    k_cvt<<<(NB * NH * NW * NC) / (256 * 8), 256, 0, stream>>>(x, xbf);
    k_demod<<<NB, 256, 0, stream>>>(kern, style, invd);
    k_wmod<<<NB * 9 * 4, 256, 0, stream>>>(kern, style, invd, wmod);
    k_conv<<<NB * NH * 2, 256, 0, stream>>>(xbf, wmod, out);
}

// Round 5
// 427.802 us; speedup vs baseline: 1.6007x; 1.6007x over previous
//
#include <hip/hip_runtime.h>
#include <hip/hip_bf16.h>

// B=8, H=W=128, C=F=256, 3x3 modulated conv (StyleGAN2), bf16 MFMA implicit GEMM.
// R5: k_conv: A single-buf (no halo, clamp+zero-select edges) + B double-buf, all
//     staging via global_load_lds, 10 barriers/chunk, LDS=40960 -> 4 blocks/CU,
//     launch_bounds(256,4) to hold VGPR<=64 (+64 acc = 128/wave = 4 waves/SIMD).
//     R4 failure: register-B prefetch after A-DMA hits vmcnt in-order retirement
//     (waiting B drains all A-DMA) + 148 regs/wave -> 3 waves/SIMD.
//     k_demod (was ~290us: 8 blocks, stride-1KB loads) -> k_part (288 blocks,
//     coalesced) + inline invd in k_wmod.

#define NB 8
#define NH 128
#define NW 128
#define NC 256
#define NF 256

typedef __attribute__((ext_vector_type(8))) short bf16x8;
typedef __attribute__((ext_vector_type(4))) float f32x4;

#define A_ROW 8192            // per dh: 4 planes x 128 pos x 16B
#define A_BUF (3 * A_ROW)     // 24576
#define B_BUF 8192            // 4 planes x 128 f x 16B
#define LDS_BYTES (A_BUF + 2 * B_BUF)  // 40960 -> exactly 4 blocks/CU

static __device__ __forceinline__ ushort f2bf(float v) {
    union { ushort u; __hip_bfloat16 h; } o;
    o.h = __float2bfloat16(v);
    return o.u;
}

__device__ __forceinline__ void gload16(const ushort* g, const char* l) {
    __builtin_amdgcn_global_load_lds(
        (const __attribute__((address_space(1))) void*)g,
        (__attribute__((address_space(3))) void*)l,
        16, 0, 0);
}

// ---------------- x fp32 -> bf16 ----------------
__global__ void k_cvt(const float* __restrict__ x, ushort* __restrict__ xbf) {
    size_t i = ((size_t)blockIdx.x * 256 + threadIdx.x) * 8;
    float4 a = *(const float4*)(x + i);
    float4 b = *(const float4*)(x + i + 4);
    union { ushort s[8]; uint4 u; } o;
    o.s[0] = f2bf(a.x); o.s[1] = f2bf(a.y);
    o.s[2] = f2bf(a.z); o.s[3] = f2bf(a.w);
    o.s[4] = f2bf(b.x); o.s[5] = f2bf(b.y);
    o.s[6] = f2bf(b.z); o.s[7] = f2bf(b.w);
    *(uint4*)(xbf + i) = o.u;
}

// ---------------- partial sum-of-squares: part[b][t][f] ----------------
// grid 288 = (b=8, t=9, fc=4); block 256 = (cq=4 x fl=64). Coalesced 256B loads.
__global__ void k_part(const float* __restrict__ kern, const float* __restrict__ style,
                       float* __restrict__ part) {
    int blk = blockIdx.x;
    int fc = blk & 3;
    int t  = (blk >> 2) % 9;
    int b  = blk / 36;
    int fl = threadIdx.x & 63, cq = threadIdx.x >> 6;
    int f = fc * 64 + fl;
    const float* kp = kern + (size_t)t * 65536 + f;
    const float* st = style + b * 256 + cq * 64;
    float acc = 0.f;
#pragma unroll 8
    for (int i = 0; i < 64; ++i) {
        float s = st[i] + 1.0f;
        float w = kp[(size_t)(cq * 64 + i) * 256] * s;
        acc += w * w;
    }
    __shared__ float red[256];
    red[threadIdx.x] = acc;
    __syncthreads();
    if (cq == 0) {
        float v = red[fl] + red[64 + fl] + red[128 + fl] + red[192 + fl];
        part[((size_t)b * 9 + t) * 256 + f] = v;
    }
}

// ---------------- modulated weights wm[b][t][f][c] bf16 (transposed) ----------------
// grid 288 = (b=8, t=9, fc=4); coalesced kern loads, LDS transpose, 16B stores.
__global__ void k_wmod(const float* __restrict__ kern, const float* __restrict__ style,
                       const float* __restrict__ part, ushort* __restrict__ wm) {
    int blk = blockIdx.x;
    int fc = blk & 3;
    int t  = (blk >> 2) % 9;
    int b  = blk / 36;
    int f0 = fc * 64;
    __shared__ ushort tile[64 * 264];
    int fl = threadIdx.x & 63;
    int cq = threadIdx.x >> 6;
    // demod factor for this thread's f (redundant across cq, cheap)
    float sum = 0.f;
#pragma unroll
    for (int tt = 0; tt < 9; ++tt) sum += part[((size_t)b * 9 + tt) * 256 + f0 + fl];
    float dv = 1.0f / sqrtf(sum + 1e-8f);
    const float* kp = kern + (size_t)t * 65536 + f0 + fl;
#pragma unroll 4
    for (int cc = 0; cc < 64; ++cc) {
        int c = cq * 64 + cc;
        float s = style[b * 256 + c] + 1.0f;
        tile[fl * 264 + c] = f2bf(kp[(size_t)c * 256] * s * dv);
    }
    __syncthreads();
    int f  = threadIdx.x >> 2;
    int c8 = threadIdx.x & 3;
    ushort* dst = wm + (((size_t)(b * 9 + t) * 256) + f0 + f) * 256;
#pragma unroll
    for (int j = 0; j < 8; ++j) {
        int c = (c8 + j * 4) * 8;
        *(uint4*)(dst + c) = *(const uint4*)(tile + f * 264 + c);
    }
}

// ---------------- conv as implicit GEMM ----------------
__global__ void __launch_bounds__(256, 4)
k_conv(const ushort* __restrict__ xbf, const ushort* __restrict__ wm,
       float* __restrict__ out) {
    const int bidx = blockIdx.x;
    const int b    = bidx & 7;        // XCD pin: image b's x stays in one XCD's L2
    const int rest = bidx >> 3;
    const int fh   = rest & 1;
    const int h    = rest >> 1;

    __shared__ __align__(16) char smem[LDS_BYTES];
    char* As = smem;                  // [dh][plane][pos] 16B units
    char* Bs = smem + A_BUF;          // 2 bufs x [plane][f] 16B units

    const int tid = threadIdx.x;
    const int wave = tid >> 6, lane = tid & 63;
    const int wm_ = wave & 1, wn_ = wave >> 1;   // 2x2 wave grid, 64x64 each
    const int lrow = lane & 15;
    const int quad = lane >> 4;

    // Edge blocks: zero A once (skipped-DMA rows must read as 0; single-buffered
    // A means they are never overwritten).
    if (h == 0 || h == 127) {
        const uint4 z = {0, 0, 0, 0};
        for (int i = tid; i < A_BUF / 16; i += 256) ((uint4*)As)[i] = z;
    }
    __syncthreads();

    f32x4 acc[4][4];
    const f32x4 zero4 = {0.f, 0.f, 0.f, 0.f};
#pragma unroll
    for (int mi = 0; mi < 4; ++mi)
#pragma unroll
        for (int ni = 0; ni < 4; ++ni) acc[mi][ni] = zero4;

    const ushort* xb_base = xbf + (size_t)b * 128 * 128 * 256;
    const ushort* wm_fh   = wm + (size_t)b * 9 * 65536 + (size_t)fh * 128 * 256;

    const bf16x8 zfrag = {0, 0, 0, 0, 0, 0, 0, 0};

    for (int k = 0; k < 8; ++k) {
        const int c0 = k * 32;
        // ---- A[k] DMA: 24 wave-loads (6/wave). Prior chunk's A reads completed
        //      at tap8's end-barrier. ----
#pragma unroll
        for (int i = 0; i < 6; ++i) {
            int L = wave * 6 + i;
            int dh = L >> 3, rem = L & 7;
            int p = rem >> 1, half = rem & 1;
            int hp = h + dh - 1;
            if (hp >= 0 && hp < 128) {
                const ushort* g = xb_base + ((size_t)hp * 128 + half * 64 + lane) * 256 + c0 + p * 8;
                const char* l = As + dh * A_ROW + p * 2048 + half * 1024 + lane * 16;
                gload16(g, l);
            }
        }
        // ---- B[k,tap0] -> buf0 (tap8 of prior chunk also used buf0; its reads
        //      completed at its end-barrier) ----
#pragma unroll
        for (int i = 0; i < 2; ++i) {
            int s = wave * 2 + i;
            int p = s >> 1, half = s & 1;
            const ushort* g = wm_fh + (size_t)(half * 64 + lane) * 256 + c0 + p * 8;
            const char* l = Bs + p * 2048 + half * 1024 + lane * 16;
            gload16(g, l);
        }
        __syncthreads();   // drain A[k] + B0 DMA; publish

#pragma unroll
        for (int t = 0; t < 9; ++t) {
            const int dh = t / 3, dw = t % 3;
            // prefetch B[k,t+1] into other buffer (its prior reader, tap t-1,
            // finished at tap t-1's end-barrier)
            if (t < 8) {
                char* nb = Bs + ((t + 1) & 1) * B_BUF;
#pragma unroll
                for (int i = 0; i < 2; ++i) {
                    int s = wave * 2 + i;
                    int p = s >> 1, half = s & 1;
                    const ushort* g = wm_fh + (size_t)(t + 1) * 65536 + (size_t)(half * 64 + lane) * 256 + c0 + p * 8;
                    const char* l = nb + p * 2048 + half * 1024 + lane * 16;
                    gload16(g, l);
                }
            }
            // ---- fragments ----
            const char* bb = Bs + (t & 1) * B_BUF;
            bf16x8 bfr[4];
#pragma unroll
            for (int ni = 0; ni < 4; ++ni) {
                int fl = wn_ * 64 + ni * 16 + lrow;
                bfr[ni] = *(const bf16x8*)(bb + quad * 2048 + fl * 16);
            }
            bf16x8 af[4];
#pragma unroll
            for (int mi = 0; mi < 4; ++mi) {
                int s = wm_ * 64 + mi * 16 + lrow + dw - 1;
                int sc = s & 127;                 // -1 -> 127, 128 -> 0
                bf16x8 v = *(const bf16x8*)(As + dh * A_ROW + quad * 2048 + sc * 16);
                if (dw == 0 && mi == 0)
                    af[mi] = (wm_ == 0 && lrow == 0) ? zfrag : v;   // s == -1
                else if (dw == 2 && mi == 3)
                    af[mi] = (wm_ == 1 && lrow == 15) ? zfrag : v;  // s == 128
                else
                    af[mi] = v;
            }
#pragma unroll
            for (int mi = 0; mi < 4; ++mi)
#pragma unroll
                for (int ni = 0; ni < 4; ++ni)
                    acc[mi][ni] = __builtin_amdgcn_mfma_f32_16x16x32_bf16(
                        af[mi], bfr[ni], acc[mi][ni], 0, 0, 0);
            __syncthreads();   // drain B[t+1] DMA; B[t] reads (lgkm) done; publish
        }
    }

    // epilogue: C/D layout col=lane&15, row=quad*4+reg
    float* obase = out + (((size_t)b * 128 + h) * 128) * 256 + fh * 128;
#pragma unroll
    for (int mi = 0; mi < 4; ++mi) {
        int wrow = wm_ * 64 + mi * 16 + quad * 4;
#pragma unroll
        for (int ni = 0; ni < 4; ++ni) {
            int f = wn_ * 64 + ni * 16 + lrow;
            f32x4 v = acc[mi][ni];
#pragma unroll
            for (int r = 0; r < 4; ++r) {
                obase[(size_t)(wrow + r) * 256 + f] = v[r];
            }
        }
    }
}

extern "C" void kernel_launch(void* const* d_in, const int* in_sizes, int n_in,
                              void* d_out, int out_size, void* d_ws, size_t ws_size,
                              hipStream_t stream) {
    const float* x     = (const float*)d_in[0];   // [8,128,128,256]
    const float* style = (const float*)d_in[1];   // [8,1,1,256]
    const float* kern  = (const float*)d_in[2];   // [3,3,256,256]
    float* out = (float*)d_out;                   // [8,128,128,256]

    ushort* xbf  = (ushort*)d_ws;                               // 64 MiB
    ushort* wmod = xbf + (size_t)NB * NH * NW * NC;             // 9 MiB
    float*  part = (float*)(wmod + (size_t)NB * 9 * NF * NC);   // 72 KiB

    k_cvt<<<(NB * NH * NW * NC) / (256 * 8), 256, 0, stream>>>(x, xbf);
    k_part<<<NB * 9 * 4, 256, 0, stream>>>(kern, style, part);
    k_wmod<<<NB * 9 * 4, 256, 0, stream>>>(kern, style, part, wmod);
    k_conv<<<NB * NH * 2, 256, 0, stream>>>(xbf, wmod, out);
}